// Round 14
// baseline (427.291 us; speedup 1.0000x reference)
//
#include <hip/hip_runtime.h>
#include <hip/hip_fp16.h>
#include <hip/hip_cooperative_groups.h>
#include <math.h>

namespace cg = cooperative_groups;

// Problem constants (match reference)
constexpr int N_NODES = 65536;
constexpr int N_EDGES = 2097152;
constexpr int F_IN    = 128;
constexpr int H_DIM   = 256;
constexpr int O_DIM   = 128;
constexpr int N_GRAPH = 256;
constexpr int V_SIZE  = 1000;

// 256 buckets of 256 nodes (bucket = col>>8); 256 edge-blocks of 8192 edges.
constexpr int EPB  = 8192;
constexpr int NBLK = N_EDGES / EPB;   // 256
constexpr float FXP = 16777216.0f;    // 2^24

typedef _Float16 half8 __attribute__((ext_vector_type(8)));
typedef float floatx4 __attribute__((ext_vector_type(4)));

// ---------------- init: pool=0, graph counts, cfW1 table, W2T fp16 (R9) -----

__global__ void k_init(float* __restrict__ pool, const int* __restrict__ batch,
                       float* __restrict__ cntf, const float* __restrict__ cf,
                       const float* __restrict__ W1, __half* __restrict__ cfW1,
                       const float* __restrict__ W2, _Float16* __restrict__ W2T) {
    __shared__ float xs[8 * F_IN];    // 4 KB
    int i = blockIdx.x * blockDim.x + threadIdx.x;
    if (i < N_GRAPH * O_DIM) pool[i] = 0.0f;
    if (blockIdx.x == 0) {
        // batch_index sorted: per-graph counts via binary search, no atomics
        int g = threadIdx.x;
        int lo = 0, hi = N_NODES;
        while (lo < hi) { int m = (lo + hi) >> 1; if (batch[m] < g) lo = m + 1; else hi = m; }
        int start = lo;
        lo = 0; hi = N_NODES;
        while (lo < hi) { int m = (lo + hi) >> 1; if (batch[m] <= g) lo = m + 1; else hi = m; }
        cntf[g] = (float)(lo - start);
    }
    if (blockIdx.x < V_SIZE / 8) {    // 125 blocks compute the cfW1 table
        int rb = blockIdx.x * 8;
        int t  = threadIdx.x;
        #pragma unroll
        for (int p = 0; p < 4; ++p) {
            int idx = p * 256 + t;
            int r = idx >> 7, k = idx & 127;
            xs[idx] = cf[(size_t)(rb + r) * F_IN + k];
        }
        __syncthreads();
        float acc[8] = {};
        for (int k = 0; k < F_IN; ++k) {
            float w = W1[k * H_DIM + t];
            #pragma unroll
            for (int j = 0; j < 8; ++j) acc[j] += xs[j * F_IN + k] * w;
        }
        #pragma unroll
        for (int j = 0; j < 8; ++j)
            cfW1[(size_t)(rb + j) * H_DIM + t] = __float2half(acc[j]);
    }
    if (blockIdx.x >= 128) {          // 128 blocks: W2T transpose fp32->fp16
        int idx = (blockIdx.x - 128) * 256 + threadIdx.x;   // 0..32767
        int nn = idx >> 8, kk = idx & 255;
        W2T[idx] = (_Float16)W2[kk * O_DIM + nn];
    }
}

// ---------------- stage A: per-block bucket histogram (256 blocks x 1024) ---

__global__ void k_hist(const int* __restrict__ col, int* __restrict__ hist) {
    __shared__ int h[256];
    int t = threadIdx.x;
    if (t < 256) h[t] = 0;
    __syncthreads();
    int base = blockIdx.x * EPB;
    #pragma unroll
    for (int i = 0; i < EPB / 1024; ++i)
        atomicAdd(&h[col[base + i * 1024 + t] >> 8], 1);
    __syncthreads();
    if (t < 256) hist[t * NBLK + blockIdx.x] = h[t];   // bucket-major for the scan
}

// ---------------- cooperative prep: scan + part + build1 + build2 -----------
// 256 blocks x 1024 threads (1 block/CU, co-resident). Phase bodies are the
// R9-verified kernels verbatim; grid.sync() replaces kernel boundaries.

__global__ void __launch_bounds__(1024) k_prep(
        const int* __restrict__ hist, int* __restrict__ hoffs, int* __restrict__ bsum,
        const int* __restrict__ row, const int* __restrict__ col,
        const float* __restrict__ ew, const int* __restrict__ nidx,
        int2* __restrict__ part, float* __restrict__ dis,
        int* __restrict__ offs, int2* __restrict__ csr) {
    __shared__ int sbuf[256];
    __shared__ int exc[257];
    __shared__ int cur[256];
    __shared__ unsigned long long dc[256];
    __shared__ int sc[256];
    cg::grid_group grid = cg::this_grid();
    int t = threadIdx.x;
    int b = blockIdx.x;

    // ---- phase 0: within-bucket scan of hist row b (bucket b) ----
    int v0 = 0;
    if (t < 256) { v0 = hist[b * 256 + t]; sbuf[t] = v0; }
    __syncthreads();
    for (int d = 1; d < 256; d <<= 1) {
        int x = (t < 256 && t >= d) ? sbuf[t - d] : 0;
        __syncthreads();
        if (t < 256) sbuf[t] += x;
        __syncthreads();
    }
    if (t < 256) hoffs[b * 256 + t] = sbuf[t] - v0;
    if (t == 255) bsum[b] = sbuf[255];
    grid.sync();

    // ---- bucket-total exclusive scan (kept in LDS for all later phases) ----
    if (t < 256) sbuf[t] = bsum[t];
    __syncthreads();
    for (int d = 1; d < 256; d <<= 1) {
        int x = (t < 256 && t >= d) ? sbuf[t - d] : 0;
        __syncthreads();
        if (t < 256) sbuf[t] += x;
        __syncthreads();
    }
    if (t < 256) exc[t + 1] = sbuf[t];
    if (t == 0) exc[0] = 0;
    __syncthreads();

    // ---- phase 1: partition edge-block b into bucket-sorted part ----
    if (t < 256) cur[t] = hoffs[t * NBLK + b] + exc[t];
    __syncthreads();
    {
        int base = b * EPB;
        #pragma unroll
        for (int i = 0; i < EPB / 1024; ++i) {
            int e = base + i * 1024 + t;
            int r = row[e], c = col[e];
            unsigned hw = (unsigned)__half_as_ushort(__float2half(ew[e]));
            int vb = nidx[r];
            int slot = atomicAdd(&cur[c >> 8], 1);
            int2 rec;
            rec.x = (r << 16) | ((c & 255) << 8) | (vb >> 2);
            rec.y = (int)(((unsigned)(vb & 3) << 16) | hw);
            part[slot] = rec;
        }
    }
    grid.sync();

    // ---- phase 2: per-bucket deg/dis + per-dst CSR offsets (bucket b) ----
    int start = exc[b];
    int end   = exc[b + 1];
    if (t < 256) dc[t] = 0ULL;
    __syncthreads();
    for (int j = start + t; j < end; j += 1024) {
        int2 rec = part[j];
        int dst = (rec.x >> 8) & 255;
        float w = __half2float(__ushort_as_half((unsigned short)(rec.y & 0xFFFF)));
        atomicAdd(&dc[dst], (1ULL << 40) |
                  (unsigned long long)(unsigned)(w * FXP + 0.5f));
    }
    __syncthreads();
    unsigned long long v = (t < 256) ? dc[t] : 0ULL;
    if (t < 256) {
        float deg = 1.0f + (float)(v & 0xFFFFFFFFFFULL) * (1.0f / FXP);   // self-loop +1
        dis[b * 256 + t] = 1.0f / sqrtf(deg);                             // deg >= 1
        sc[t] = (int)(v >> 40);
    }
    __syncthreads();
    for (int d = 1; d < 256; d <<= 1) {
        int x = (t >= d && t < 256) ? sc[t - d] : 0;
        __syncthreads();
        if (t < 256) sc[t] += x;
        __syncthreads();
    }
    if (t < 256) {
        int cnt = (int)(v >> 40);
        offs[b * 256 + t] = start + sc[t] - cnt;
    }
    if (b == 255 && t == 255) offs[N_NODES] = N_EDGES;
    grid.sync();

    // ---- phase 3: scatter to final CSR with nrm applied (bucket b) ----
    if (t < 256) cur[t] = offs[b * 256 + t];
    __syncthreads();
    for (int j = start + t; j < end; j += 1024) {
        int2 rec = part[j];
        int dst = (rec.x >> 8) & 255;
        unsigned src = ((unsigned)rec.x) >> 16;
        int vb = ((rec.x & 255) << 2) | ((rec.y >> 16) & 3);
        float w = __half2float(__ushort_as_half((unsigned short)(rec.y & 0xFFFF)));
        float nm = dis[src] * w;
        int slot = atomicAdd(&cur[dst], 1);
        int2 e;
        e.x = (int)((src << 10) | (unsigned)vb);
        e.y = __float_as_int(nm);
        csr[slot] = e;
    }
}

// ============ fallback path (regular launches, R12-proven bodies) ===========

__global__ void k_scan1(const int* __restrict__ in, int* __restrict__ out,
                        int* __restrict__ bsum) {
    __shared__ int s[256];
    int tid = threadIdx.x;
    int i = blockIdx.x * 256 + tid;
    int v = in[i];
    s[tid] = v;
    __syncthreads();
    for (int d = 1; d < 256; d <<= 1) {
        int t = (tid >= d) ? s[tid - d] : 0;
        __syncthreads();
        s[tid] += t;
        __syncthreads();
    }
    out[i] = s[tid] - v;
    if (tid == 255) bsum[blockIdx.x] = s[255];
}

__device__ __forceinline__ void scan_bsum(const int* __restrict__ bsum,
                                          int* __restrict__ sbuf,
                                          int* __restrict__ exc, int t) {
    if (t < 256) sbuf[t] = bsum[t];
    __syncthreads();
    for (int d = 1; d < 256; d <<= 1) {
        int x = (t < 256 && t >= d) ? sbuf[t - d] : 0;
        __syncthreads();
        if (t < 256) sbuf[t] += x;
        __syncthreads();
    }
    if (t < 256) exc[t + 1] = sbuf[t];
    if (t == 0) exc[0] = 0;
    __syncthreads();
}

__global__ void k_part(const int* __restrict__ row, const int* __restrict__ col,
                       const float* __restrict__ ew, const int* __restrict__ nidx,
                       const int* __restrict__ hoffs, const int* __restrict__ bsum,
                       int2* __restrict__ part) {
    __shared__ int cur[256];
    __shared__ int sbuf[256];
    __shared__ int exc[257];
    int t = threadIdx.x;
    scan_bsum(bsum, sbuf, exc, t);
    if (t < 256) cur[t] = hoffs[t * NBLK + blockIdx.x] + exc[t];
    __syncthreads();
    int base = blockIdx.x * EPB;
    #pragma unroll
    for (int i = 0; i < EPB / 1024; ++i) {
        int e = base + i * 1024 + t;
        int r = row[e], c = col[e];
        unsigned hw = (unsigned)__half_as_ushort(__float2half(ew[e]));
        int vb = nidx[r];
        int slot = atomicAdd(&cur[c >> 8], 1);
        int2 rec;
        rec.x = (r << 16) | ((c & 255) << 8) | (vb >> 2);
        rec.y = (int)(((unsigned)(vb & 3) << 16) | hw);
        part[slot] = rec;
    }
}

__global__ void k_build1(const int* __restrict__ hoffs, const int* __restrict__ bsum,
                         const int2* __restrict__ part, float* __restrict__ dis,
                         int* __restrict__ offs) {
    __shared__ unsigned long long dc[256];
    __shared__ int sc[256];
    __shared__ int sbuf[256];
    __shared__ int exc[257];
    int t = threadIdx.x;
    int bucket = blockIdx.x;
    scan_bsum(bsum, sbuf, exc, t);
    if (t < 256) dc[t] = 0ULL;
    __syncthreads();
    int start = exc[bucket];
    int end   = exc[bucket + 1];
    for (int j = start + t; j < end; j += 1024) {
        int2 rec = part[j];
        int dst = (rec.x >> 8) & 255;
        float w = __half2float(__ushort_as_half((unsigned short)(rec.y & 0xFFFF)));
        atomicAdd(&dc[dst], (1ULL << 40) |
                  (unsigned long long)(unsigned)(w * FXP + 0.5f));
    }
    __syncthreads();
    unsigned long long v = (t < 256) ? dc[t] : 0ULL;
    if (t < 256) {
        float deg = 1.0f + (float)(v & 0xFFFFFFFFFFULL) * (1.0f / FXP);   // self-loop +1
        dis[bucket * 256 + t] = 1.0f / sqrtf(deg);                        // deg >= 1
        sc[t] = (int)(v >> 40);
    }
    __syncthreads();
    for (int d = 1; d < 256; d <<= 1) {
        int x = (t >= d && t < 256) ? sc[t - d] : 0;
        __syncthreads();
        if (t < 256) sc[t] += x;
        __syncthreads();
    }
    if (t < 256) {
        int cnt = (int)(v >> 40);
        offs[bucket * 256 + t] = start + sc[t] - cnt;
    }
    if (bucket == 255 && t == 255) offs[N_NODES] = N_EDGES;
}

__global__ void k_build2(const int* __restrict__ hoffs, const int* __restrict__ bsum,
                         const int2* __restrict__ part, const float* __restrict__ dis,
                         const int* __restrict__ offs, int2* __restrict__ csr) {
    __shared__ int cur[256];
    __shared__ int sbuf[256];
    __shared__ int exc[257];
    int t = threadIdx.x;
    int bucket = blockIdx.x;
    scan_bsum(bsum, sbuf, exc, t);
    if (t < 256) cur[t] = offs[bucket * 256 + t];
    __syncthreads();
    int start = exc[bucket];
    int end   = exc[bucket + 1];
    for (int j = start + t; j < end; j += 1024) {
        int2 rec = part[j];
        int dst = (rec.x >> 8) & 255;
        unsigned src = ((unsigned)rec.x) >> 16;
        int vb = ((rec.x & 255) << 2) | ((rec.y >> 16) & 3);
        float w = __half2float(__ushort_as_half((unsigned short)(rec.y & 0xFFFF)));
        float nm = dis[src] * w;
        int slot = atomicAdd(&cur[dst], 1);
        int2 e;
        e.x = (int)((src << 10) | (unsigned)vb);
        e.y = __float_as_int(nm);
        csr[slot] = e;
    }
}

// 8-half fp16 row-fragment accumulate: e[k] += f32(v[k]) * n
__device__ __forceinline__ void acc8(float* e, int4 v, float n) {
    float2 f0 = __half22float2(*(__half2*)&v.x);
    float2 f1 = __half22float2(*(__half2*)&v.y);
    float2 f2 = __half22float2(*(__half2*)&v.z);
    float2 f3 = __half22float2(*(__half2*)&v.w);
    e[0] += f0.x * n; e[1] += f0.y * n;
    e[2] += f1.x * n; e[3] += f1.y * n;
    e[4] += f2.x * n; e[5] += f2.y * n;
    e[6] += f3.x * n; e[7] += f3.y * n;
}

// ---------------- layer-1: gather-aggregate cfW1 rows -> h1 (R9-exact) ------

__global__ void k_agg1(const int4* __restrict__ cfW1, const int* __restrict__ nidx,
                       const float* __restrict__ dis, const int* __restrict__ offs,
                       const int2* __restrict__ csr, const float4* __restrict__ b1f4,
                       int4* __restrict__ h1) {
    int wave = threadIdx.x >> 6;
    int lane = threadIdx.x & 63;
    int g    = lane >> 5;        // which edge of the pair
    int sl   = lane & 31;        // int4 slot within the 256-half row
    int c = blockIdx.x * 4 + wave;
    float d = dis[c];
    int4 sp = cfW1[(size_t)nidx[c] * 32 + sl];
    float esum[8] = {0.f, 0.f, 0.f, 0.f, 0.f, 0.f, 0.f, 0.f};
    int a0 = offs[c], a1 = offs[c + 1];
    int s = a0;
    // peel one edge if start is odd (keeps scalar int4 loads 16B-aligned)
    if (s < a1 && (s & 1)) {
        int sb = __builtin_amdgcn_readfirstlane(s);
        int2 e0 = csr[sb];
        int4 v0 = cfW1[(size_t)(e0.x & 1023) * 32 + sl];
        float n = (g == 0) ? __int_as_float(e0.y) : 0.0f;
        acc8(esum, v0, n);
        ++s;
    }
    // main: 4 pairs (8 edges) per batch, 4 int4 gathers in flight
    for (; s + 8 <= a1; s += 8) {
        int sb = __builtin_amdgcn_readfirstlane(s);
        int4 ee[4];
        #pragma unroll
        for (int u = 0; u < 4; ++u) ee[u] = *(const int4*)(csr + sb + 2 * u);
        int4 v[4]; float n[4];
        #pragma unroll
        for (int u = 0; u < 4; ++u) {
            int ex = g ? ee[u].z : ee[u].x;
            int ey = g ? ee[u].w : ee[u].y;
            n[u] = __int_as_float(ey);
            v[u] = cfW1[(size_t)(ex & 1023) * 32 + sl];
        }
        #pragma unroll
        for (int u = 0; u < 4; ++u) acc8(esum, v[u], n[u]);
    }
    // pair tail
    for (; s + 2 <= a1; s += 2) {
        int sb = __builtin_amdgcn_readfirstlane(s);
        int4 ee = *(const int4*)(csr + sb);
        int ex = g ? ee.z : ee.x;
        int ey = g ? ee.w : ee.y;
        int4 v0 = cfW1[(size_t)(ex & 1023) * 32 + sl];
        acc8(esum, v0, __int_as_float(ey));
    }
    // single tail
    if (s < a1) {
        int sb = __builtin_amdgcn_readfirstlane(s);
        int2 e0 = csr[sb];
        int4 v0 = cfW1[(size_t)(e0.x & 1023) * 32 + sl];
        float n = (g == 0) ? __int_as_float(e0.y) : 0.0f;
        acc8(esum, v0, n);
    }
    // combine the two half-wave partial sums
    #pragma unroll
    for (int k = 0; k < 8; ++k) esum[k] += __shfl_xor(esum[k], 32, 64);

    float dd = d * d;
    float2 s0 = __half22float2(*(__half2*)&sp.x);
    float2 s1 = __half22float2(*(__half2*)&sp.y);
    float2 s2 = __half22float2(*(__half2*)&sp.z);
    float2 s3 = __half22float2(*(__half2*)&sp.w);
    float4 bb0 = b1f4[2 * sl];
    float4 bb1 = b1f4[2 * sl + 1];
    float r[8];
    r[0] = bb0.x + s0.x * dd + d * esum[0];
    r[1] = bb0.y + s0.y * dd + d * esum[1];
    r[2] = bb0.z + s1.x * dd + d * esum[2];
    r[3] = bb0.w + s1.y * dd + d * esum[3];
    r[4] = bb1.x + s2.x * dd + d * esum[4];
    r[5] = bb1.y + s2.y * dd + d * esum[5];
    r[6] = bb1.z + s3.x * dd + d * esum[6];
    r[7] = bb1.w + s3.y * dd + d * esum[7];
    #pragma unroll
    for (int k = 0; k < 8; ++k) r[k] = r[k] > 0.f ? r[k] : 0.f;
    float2 p0 = {r[0], r[1]}, p1 = {r[2], r[3]}, p2 = {r[4], r[5]}, p3 = {r[6], r[7]};
    __half2 h0 = __float22half2_rn(p0);
    __half2 h1v = __float22half2_rn(p1);
    __half2 h2 = __float22half2_rn(p2);
    __half2 h3 = __float22half2_rn(p3);
    int4 outv;
    outv.x = *(int*)&h0;
    outv.y = *(int*)&h1v;
    outv.z = *(int*)&h2;
    outv.w = *(int*)&h3;
    if (lane < 32) h1[(size_t)c * 32 + sl] = outv;
}

// ---------------- GEMM2 via MFMA: h1 [N,256] fp16 @ W2 -> xw2h fp16 ---------

__global__ void k_gemm2(const _Float16* __restrict__ h1, const _Float16* __restrict__ W2T,
                        __half* __restrict__ xw2h) {
    int wave = threadIdx.x >> 6;
    int lane = threadIdx.x & 63;
    int quad = lane >> 4;
    int n    = lane & 15;
    int tm   = blockIdx.x * 4 + wave;                  // 16-row tile index
    const _Float16* arow = h1 + (size_t)(tm * 16 + n) * H_DIM;
    half8 a[8];
    #pragma unroll
    for (int kt = 0; kt < 8; ++kt)
        a[kt] = *(const half8*)(arow + kt * 32 + quad * 8);
    #pragma unroll
    for (int nt = 0; nt < 8; ++nt) {
        floatx4 acc = {0.f, 0.f, 0.f, 0.f};
        const _Float16* brow = W2T + (size_t)(nt * 16 + n) * H_DIM;
        #pragma unroll
        for (int kt = 0; kt < 8; ++kt) {
            half8 b = *(const half8*)(brow + kt * 32 + quad * 8);
            acc = __builtin_amdgcn_mfma_f32_16x16x32_f16(a[kt], b, acc, 0, 0, 0);
        }
        #pragma unroll
        for (int r = 0; r < 4; ++r) {
            int rowi = tm * 16 + quad * 4 + r;
            xw2h[(size_t)rowi * O_DIM + nt * 16 + n] = __float2half(acc[r]);
        }
    }
}

// ---------------- layer-2 agg + relu + LDS-reduced pool (R1-exact) ----------

__global__ void k_agg2_pool(const int4* __restrict__ xw2h, const float* __restrict__ b2,
                            const float* __restrict__ dis, const int* __restrict__ offs,
                            const int2* __restrict__ csr, const int* __restrict__ batch,
                            float* __restrict__ pool) {
    __shared__ float red[4][128];
    __shared__ int bgs[4];
    int wave = threadIdx.x >> 6;
    int lane = threadIdx.x & 63;
    int grp  = lane >> 4;        // which edge of the quad
    int sl   = lane & 15;        // int4 slot within the 128-half row
    int c = blockIdx.x * 4 + wave;
    float d = dis[c];
    int4 sp = xw2h[(size_t)c * 16 + sl];
    float esum[8] = {0.f, 0.f, 0.f, 0.f, 0.f, 0.f, 0.f, 0.f};
    int s0 = offs[c], s1 = offs[c + 1];
    int s = s0;
    // main: 4 quads (16 edges) per batch, 4 int4 gathers in flight
    for (; s + 16 <= s1; s += 16) {
        int sb = __builtin_amdgcn_readfirstlane(s);
        int2 e[4];
        #pragma unroll
        for (int u = 0; u < 4; ++u) e[u] = csr[sb + 4 * u + grp];
        int4 v[4];
        #pragma unroll
        for (int u = 0; u < 4; ++u)
            v[u] = xw2h[(size_t)(((unsigned)e[u].x) >> 10) * 16 + sl];
        #pragma unroll
        for (int u = 0; u < 4; ++u) acc8(esum, v[u], __int_as_float(e[u].y));
    }
    // quad tail
    for (; s + 4 <= s1; s += 4) {
        int sb = __builtin_amdgcn_readfirstlane(s);
        int2 e0 = csr[sb + grp];
        int4 v0 = xw2h[(size_t)(((unsigned)e0.x) >> 10) * 16 + sl];
        acc8(esum, v0, __int_as_float(e0.y));
    }
    // remainder 0..3 edges: clamp index, zero weight for invalid lanes
    if (s < s1) {
        int sb = __builtin_amdgcn_readfirstlane(s);
        int idx = sb + grp;
        int idc = idx < s1 ? idx : s1 - 1;
        int2 e0 = csr[idc];
        int4 v0 = xw2h[(size_t)(((unsigned)e0.x) >> 10) * 16 + sl];
        float n = (idx < s1) ? __int_as_float(e0.y) : 0.0f;
        acc8(esum, v0, n);
    }
    // combine the 4 lane-group partial sums
    #pragma unroll
    for (int k = 0; k < 8; ++k) {
        esum[k] += __shfl_xor(esum[k], 16, 64);
        esum[k] += __shfl_xor(esum[k], 32, 64);
    }
    float dd = d * d;
    float2 f0 = __half22float2(*(__half2*)&sp.x);
    float2 f1 = __half22float2(*(__half2*)&sp.y);
    float2 f2 = __half22float2(*(__half2*)&sp.z);
    float2 f3 = __half22float2(*(__half2*)&sp.w);
    float4 bb0 = ((const float4*)b2)[2 * sl];
    float4 bb1 = ((const float4*)b2)[2 * sl + 1];
    float acc[8];
    acc[0] = bb0.x + f0.x * dd + d * esum[0];
    acc[1] = bb0.y + f0.y * dd + d * esum[1];
    acc[2] = bb0.z + f1.x * dd + d * esum[2];
    acc[3] = bb0.w + f1.y * dd + d * esum[3];
    acc[4] = bb1.x + f2.x * dd + d * esum[4];
    acc[5] = bb1.y + f2.y * dd + d * esum[5];
    acc[6] = bb1.z + f3.x * dd + d * esum[6];
    acc[7] = bb1.w + f3.y * dd + d * esum[7];
    #pragma unroll
    for (int k = 0; k < 8; ++k) acc[k] = acc[k] > 0.f ? acc[k] : 0.f;
    if (grp == 0) {
        #pragma unroll
        for (int k = 0; k < 8; ++k) red[wave][8 * sl + k] = acc[k];
    }
    if (lane == 0) bgs[wave] = batch[c];
    __syncthreads();
    if (wave == 0) {
        float2 a;
        a.x = red[0][2 * lane];
        a.y = red[0][2 * lane + 1];
        int cg = bgs[0];
        #pragma unroll
        for (int w = 1; w < 4; ++w) {
            int g = bgs[w];
            float2 r;
            r.x = red[w][2 * lane];
            r.y = red[w][2 * lane + 1];
            if (g == cg) { a.x += r.x; a.y += r.y; }
            else {
                atomicAdd(&pool[cg * O_DIM + 2 * lane], a.x);
                atomicAdd(&pool[cg * O_DIM + 2 * lane + 1], a.y);
                a = r; cg = g;
            }
        }
        atomicAdd(&pool[cg * O_DIM + 2 * lane], a.x);
        atomicAdd(&pool[cg * O_DIM + 2 * lane + 1], a.y);
    }
}

__global__ void k_final(const float* __restrict__ pool, const float* __restrict__ cnt,
                        float* __restrict__ out) {
    int t = blockIdx.x * blockDim.x + threadIdx.x;
    if (t < N_GRAPH * O_DIM) {
        int g = t / O_DIM;
        out[t] = pool[t] / fmaxf(cnt[g], 1.0f);
    }
}

// ---------------- launch ----------------

extern "C" void kernel_launch(void* const* d_in, const int* in_sizes, int n_in,
                              void* d_out, int out_size, void* d_ws, size_t ws_size,
                              hipStream_t stream) {
    const float* cf   = (const float*)d_in[0];   // [V,128]
    const float* W1   = (const float*)d_in[1];   // [128,256]
    const float* b1   = (const float*)d_in[2];   // [256]
    const float* W2   = (const float*)d_in[3];   // [256,128]
    const float* b2   = (const float*)d_in[4];   // [128]
    const float* ew   = (const float*)d_in[5];   // [E]
    const int*   nidx = (const int*)d_in[6];     // [N]
    const int*   eidx = (const int*)d_in[7];     // [2,E]
    const int*   bidx = (const int*)d_in[8];     // [N]
    float* out = (float*)d_out;

    const int* row = eidx;            // source
    const int* col = eidx + N_EDGES;  // target

    // workspace layout (bytes)
    char* ws = (char*)d_ws;
    size_t off = 0;
    int*   hist  = (int*)  (ws + off); off += (size_t)N_NODES * 4;          // 256K
    int*   hoffs = (int*)  (ws + off); off += (size_t)N_NODES * 4;          // 256K
    int*   bsum  = (int*)  (ws + off); off += 4096;
    float* dis   = (float*)(ws + off); off += (size_t)N_NODES * 4;          // 256K
    int*   offs  = (int*)  (ws + off); off += (size_t)(N_NODES + 16) * 4;   // 256K
    int2*  csr   = (int2*) (ws + off); off += (size_t)N_EDGES * 8;          // 16M
    float* pool  = (float*)(ws + off); off += (size_t)(N_GRAPH * O_DIM + N_GRAPH) * 4;
    __half* cfW1 = (__half*)(ws + off); off += (size_t)V_SIZE * H_DIM * 2;  // 512K
    _Float16* W2T = (_Float16*)(ws + off); off += (size_t)O_DIM * H_DIM * 2; // 64K
    off = (off + 255) & ~(size_t)255;
    int2*  part  = (int2*) (ws + off); off += (size_t)N_EDGES * 8;          // 16M
    __half* h1   = (__half*)(ws + off);                                     // 32M
    __half* xw2h = (__half*)part;    // part dead after prep
    float* cntf  = pool + N_GRAPH * O_DIM;

    // 1. init (pool zero + counts + cfW1 + W2T) + histogram
    k_init<<<256, 256, 0, stream>>>(pool, bidx, cntf, cf, W1, cfW1, W2, W2T);
    k_hist<<<NBLK, 1024, 0, stream>>>(col, hist);

    // 2. prep: cooperative fused (scan+part+build1+build2); fall back to the
    //    proven split-kernel path if cooperative launch is rejected here.
    {
        const int* hist_c = hist;
        void* args[] = {(void*)&hist_c, (void*)&hoffs, (void*)&bsum,
                        (void*)&row, (void*)&col, (void*)&ew, (void*)&nidx,
                        (void*)&part, (void*)&dis, (void*)&offs, (void*)&csr};
        hipError_t err = hipLaunchCooperativeKernel((const void*)k_prep, dim3(256),
                                                    dim3(1024), args, 0, stream);
        if (err != hipSuccess) {
            k_scan1<<<256, 256, 0, stream>>>(hist, hoffs, bsum);
            k_part<<<NBLK, 1024, 0, stream>>>(row, col, ew, nidx, hoffs, bsum, part);
            k_build1<<<256, 1024, 0, stream>>>(hoffs, bsum, part, dis, offs);
            k_build2<<<256, 1024, 0, stream>>>(hoffs, bsum, part, dis, offs, csr);
        }
    }

    // 3. layer 1: gather-aggregate from the 512 KB cfW1 table -> h1 (fp16)
    k_agg1<<<N_NODES / 4, 256, 0, stream>>>((const int4*)cfW1, nidx, dis, offs, csr,
                                            (const float4*)b1, (int4*)h1);

    // 4. layer 2: MFMA GEMM2, then aggregate + relu + LDS-reduced pool
    k_gemm2<<<N_NODES / 64, 256, 0, stream>>>((const _Float16*)h1, W2T, xw2h);
    k_agg2_pool<<<N_NODES / 4, 256, 0, stream>>>((const int4*)xw2h, b2, dis, offs, csr,
                                                 bidx, pool);

    // 5. final divide
    k_final<<<(N_GRAPH * O_DIM + 255) / 256, 256, 0, stream>>>(pool, cntf, out);
}

// Round 16
// 315.133 us; speedup vs baseline: 1.3559x; 1.3559x over previous
//
#include <hip/hip_runtime.h>
#include <hip/hip_fp16.h>
#include <math.h>

// Problem constants (match reference)
constexpr int N_NODES = 65536;
constexpr int N_EDGES = 2097152;
constexpr int F_IN    = 128;
constexpr int H_DIM   = 256;
constexpr int O_DIM   = 128;
constexpr int N_GRAPH = 256;
constexpr int V_SIZE  = 1000;

// 256 buckets of 256 nodes (bucket = col>>8); 256 edge-blocks of 8192 edges.
constexpr int EPB  = 8192;
constexpr int NBLK = N_EDGES / EPB;   // 256
constexpr float FXP = 16777216.0f;    // 2^24
constexpr int BUFMAX = 10240;         // build2 LDS segment capacity (22 sigma)

typedef _Float16 half8 __attribute__((ext_vector_type(8)));
typedef float floatx4 __attribute__((ext_vector_type(4)));

// ---------------- init: pool=0, graph counts, cfW1 table, W2T fp16 (R9) -----

__global__ void k_init(float* __restrict__ pool, const int* __restrict__ batch,
                       float* __restrict__ cntf, const float* __restrict__ cf,
                       const float* __restrict__ W1, __half* __restrict__ cfW1,
                       const float* __restrict__ W2, _Float16* __restrict__ W2T) {
    __shared__ float xs[8 * F_IN];    // 4 KB
    int i = blockIdx.x * blockDim.x + threadIdx.x;
    if (i < N_GRAPH * O_DIM) pool[i] = 0.0f;
    if (blockIdx.x == 0) {
        // batch_index sorted: per-graph counts via binary search, no atomics
        int g = threadIdx.x;
        int lo = 0, hi = N_NODES;
        while (lo < hi) { int m = (lo + hi) >> 1; if (batch[m] < g) lo = m + 1; else hi = m; }
        int start = lo;
        lo = 0; hi = N_NODES;
        while (lo < hi) { int m = (lo + hi) >> 1; if (batch[m] <= g) lo = m + 1; else hi = m; }
        cntf[g] = (float)(lo - start);
    }
    if (blockIdx.x < V_SIZE / 8) {    // 125 blocks compute the cfW1 table
        int rb = blockIdx.x * 8;
        int t  = threadIdx.x;
        #pragma unroll
        for (int p = 0; p < 4; ++p) {
            int idx = p * 256 + t;
            int r = idx >> 7, k = idx & 127;
            xs[idx] = cf[(size_t)(rb + r) * F_IN + k];
        }
        __syncthreads();
        float acc[8] = {};
        for (int k = 0; k < F_IN; ++k) {
            float w = W1[k * H_DIM + t];
            #pragma unroll
            for (int j = 0; j < 8; ++j) acc[j] += xs[j * F_IN + k] * w;
        }
        #pragma unroll
        for (int j = 0; j < 8; ++j)
            cfW1[(size_t)(rb + j) * H_DIM + t] = __float2half(acc[j]);
    }
    if (blockIdx.x >= 128) {          // 128 blocks: W2T transpose fp32->fp16
        int idx = (blockIdx.x - 128) * 256 + threadIdx.x;   // 0..32767
        int nn = idx >> 8, kk = idx & 255;
        W2T[idx] = (_Float16)W2[kk * O_DIM + nn];
    }
}

// ---------------- stage A: per-block bucket histogram (256 blocks x 1024) ---

__global__ void k_hist(const int* __restrict__ col, int* __restrict__ hist) {
    __shared__ int h[256];
    int t = threadIdx.x;
    if (t < 256) h[t] = 0;
    __syncthreads();
    int base = blockIdx.x * EPB;
    #pragma unroll
    for (int i = 0; i < EPB / 1024; ++i)
        atomicAdd(&h[col[base + i * 1024 + t] >> 8], 1);
    __syncthreads();
    if (t < 256) hist[t * NBLK + blockIdx.x] = h[t];   // bucket-major for the scan
}

// ---------------- scan (partial per-256-chunk + raw chunk sums) -------------

__global__ void k_scan1(const int* __restrict__ in, int* __restrict__ out,
                        int* __restrict__ bsum) {
    __shared__ int s[256];
    int tid = threadIdx.x;
    int i = blockIdx.x * 256 + tid;
    int v = in[i];
    s[tid] = v;
    __syncthreads();
    for (int d = 1; d < 256; d <<= 1) {
        int t = (tid >= d) ? s[tid - d] : 0;
        __syncthreads();
        s[tid] += t;
        __syncthreads();
    }
    out[i] = s[tid] - v;
    if (tid == 255) bsum[blockIdx.x] = s[255];
}

// inline 256-wide exclusive scan of raw bsum -> exc[0..256] (all threads barrier)
__device__ __forceinline__ void scan_bsum(const int* __restrict__ bsum,
                                          int* __restrict__ sbuf,
                                          int* __restrict__ exc, int t) {
    if (t < 256) sbuf[t] = bsum[t];
    __syncthreads();
    for (int d = 1; d < 256; d <<= 1) {
        int x = (t < 256 && t >= d) ? sbuf[t - d] : 0;
        __syncthreads();
        if (t < 256) sbuf[t] += x;
        __syncthreads();
    }
    if (t < 256) exc[t + 1] = sbuf[t];
    if (t == 0) exc[0] = 0;
    __syncthreads();
}

// ---------------- stage C: LDS-staged partition (256 blocks x 1024) ---------
// Records bin into a 64 KB LDS buffer (cheap random LDS writes), then stream
// out linearly: destinations are piecewise-contiguous runs (~32 edges per
// (block,bucket)) -> ~20x fewer global write transactions than direct scatter.
// rec.x = src:16 | dst8:8 | vocab_hi:8 ; rec.y = vocab_lo:2<<16 | ew_fp16:16

__global__ void __launch_bounds__(1024) k_part(
        const int* __restrict__ row, const int* __restrict__ col,
        const float* __restrict__ ew, const int* __restrict__ nidx,
        const int* __restrict__ hoffs, const int* __restrict__ bsum,
        int2* __restrict__ part) {
    __shared__ int2 buf[EPB];            // 64 KB
    __shared__ unsigned char sbk[EPB];   // 8 KB
    __shared__ int h[256];
    __shared__ int lcur[256];
    __shared__ int wbase[256];
    __shared__ int sbuf[256];
    __shared__ int exc[257];
    int t = threadIdx.x;
    int blk = blockIdx.x;
    scan_bsum(bsum, sbuf, exc, t);
    if (t < 256) h[t] = 0;
    __syncthreads();
    int2 recs[8];
    int bks[8];
    int base = blk * EPB;
    #pragma unroll
    for (int i = 0; i < 8; ++i) {
        int e = base + i * 1024 + t;
        int r = row[e], c = col[e];
        unsigned hw = (unsigned)__half_as_ushort(__float2half(ew[e]));
        int vb = nidx[r];
        recs[i].x = (r << 16) | ((c & 255) << 8) | (vb >> 2);
        recs[i].y = (int)(((unsigned)(vb & 3) << 16) | hw);
        bks[i] = c >> 8;
        atomicAdd(&h[bks[i]], 1);
    }
    __syncthreads();
    // exclusive prefix of local counts -> scatter cursors + writeout bases
    if (t < 256) sbuf[t] = h[t];
    __syncthreads();
    for (int d = 1; d < 256; d <<= 1) {
        int x = (t < 256 && t >= d) ? sbuf[t - d] : 0;
        __syncthreads();
        if (t < 256) sbuf[t] += x;
        __syncthreads();
    }
    if (t < 256) {
        int ls = sbuf[t] - h[t];               // local start of bucket t
        lcur[t] = ls;
        wbase[t] = hoffs[t * NBLK + blk] + exc[t] - ls;
    }
    __syncthreads();
    #pragma unroll
    for (int i = 0; i < 8; ++i) {
        int slot = atomicAdd(&lcur[bks[i]], 1);
        buf[slot] = recs[i];
        sbk[slot] = (unsigned char)bks[i];
    }
    __syncthreads();
    // linear drain: consecutive threads hit (mostly) consecutive global slots
    #pragma unroll
    for (int i = 0; i < 8; ++i) {
        int j = i * 1024 + t;
        part[wbase[sbk[j]] + j] = buf[j];
    }
}

// ---------------- stage D1: per-bucket deg/dis + offs (256 blocks x 1024) ---

__global__ void k_build1(const int* __restrict__ bsum,
                         const int2* __restrict__ part, float* __restrict__ dis,
                         int* __restrict__ offs) {
    __shared__ unsigned long long dc[256];
    __shared__ int sc[256];
    __shared__ int sbuf[256];
    __shared__ int exc[257];
    int t = threadIdx.x;
    int bucket = blockIdx.x;
    scan_bsum(bsum, sbuf, exc, t);
    if (t < 256) dc[t] = 0ULL;
    __syncthreads();
    int start = exc[bucket];
    int end   = exc[bucket + 1];
    for (int j = start + t; j < end; j += 1024) {
        int2 rec = part[j];
        int dst = (rec.x >> 8) & 255;
        float w = __half2float(__ushort_as_half((unsigned short)(rec.y & 0xFFFF)));
        atomicAdd(&dc[dst], (1ULL << 40) |
                  (unsigned long long)(unsigned)(w * FXP + 0.5f));
    }
    __syncthreads();
    unsigned long long v = (t < 256) ? dc[t] : 0ULL;
    if (t < 256) {
        float deg = 1.0f + (float)(v & 0xFFFFFFFFFFULL) * (1.0f / FXP);   // self-loop +1
        dis[bucket * 256 + t] = 1.0f / sqrtf(deg);                        // deg >= 1
        sc[t] = (int)(v >> 40);
    }
    __syncthreads();
    for (int d = 1; d < 256; d <<= 1) {
        int x = (t >= d && t < 256) ? sc[t - d] : 0;
        __syncthreads();
        if (t < 256) sc[t] += x;
        __syncthreads();
    }
    if (t < 256) {
        int cnt = (int)(v >> 40);
        offs[bucket * 256 + t] = start + sc[t] - cnt;
    }
    if (bucket == 255 && t == 255) offs[N_NODES] = N_EDGES;
}

// ---------------- stage D2: LDS-staged CSR scatter (256 blocks x 1024) ------
// Within a bucket the dst-sorted CSR segment is an exact permutation of the
// part segment: bin into LDS via per-dst cursors (offs - start), then copy
// buf[j] -> csr[start+j] perfectly coalesced. Direct-scatter fallback if a
// segment ever exceeds BUFMAX (never expected: 22 sigma).

__global__ void __launch_bounds__(1024) k_build2(
        const int* __restrict__ bsum, const int2* __restrict__ part,
        const float* __restrict__ dis, const int* __restrict__ offs,
        int2* __restrict__ csr) {
    __shared__ int2 buf[BUFMAX];   // 80 KB
    __shared__ int cur[256];
    __shared__ int sbuf[256];
    __shared__ int exc[257];
    int t = threadIdx.x;
    int bucket = blockIdx.x;
    scan_bsum(bsum, sbuf, exc, t);
    int start = exc[bucket];
    int end   = exc[bucket + 1];
    int len   = end - start;
    if (len <= BUFMAX) {
        if (t < 256) cur[t] = offs[bucket * 256 + t] - start;
        __syncthreads();
        for (int j = start + t; j < end; j += 1024) {
            int2 rec = part[j];
            int dst = (rec.x >> 8) & 255;
            unsigned src = ((unsigned)rec.x) >> 16;
            int vb = ((rec.x & 255) << 2) | ((rec.y >> 16) & 3);
            float w = __half2float(__ushort_as_half((unsigned short)(rec.y & 0xFFFF)));
            float nm = dis[src] * w;
            int slot = atomicAdd(&cur[dst], 1);
            int2 e;
            e.x = (int)((src << 10) | (unsigned)vb);
            e.y = __float_as_int(nm);
            buf[slot] = e;
        }
        __syncthreads();
        for (int j = t; j < len; j += 1024)
            csr[start + j] = buf[j];
    } else {
        if (t < 256) cur[t] = offs[bucket * 256 + t];
        __syncthreads();
        for (int j = start + t; j < end; j += 1024) {
            int2 rec = part[j];
            int dst = (rec.x >> 8) & 255;
            unsigned src = ((unsigned)rec.x) >> 16;
            int vb = ((rec.x & 255) << 2) | ((rec.y >> 16) & 3);
            float w = __half2float(__ushort_as_half((unsigned short)(rec.y & 0xFFFF)));
            float nm = dis[src] * w;
            int slot = atomicAdd(&cur[dst], 1);
            int2 e;
            e.x = (int)((src << 10) | (unsigned)vb);
            e.y = __float_as_int(nm);
            csr[slot] = e;
        }
    }
}

// 8-half fp16 row-fragment accumulate: e[k] += f32(v[k]) * n
__device__ __forceinline__ void acc8(float* e, int4 v, float n) {
    float2 f0 = __half22float2(*(__half2*)&v.x);
    float2 f1 = __half22float2(*(__half2*)&v.y);
    float2 f2 = __half22float2(*(__half2*)&v.z);
    float2 f3 = __half22float2(*(__half2*)&v.w);
    e[0] += f0.x * n; e[1] += f0.y * n;
    e[2] += f1.x * n; e[3] += f1.y * n;
    e[4] += f2.x * n; e[5] += f2.y * n;
    e[6] += f3.x * n; e[7] += f3.y * n;
}

// ---------------- layer-1: gather-aggregate cfW1 rows -> h1 (R9-exact) ------

__global__ void k_agg1(const int4* __restrict__ cfW1, const int* __restrict__ nidx,
                       const float* __restrict__ dis, const int* __restrict__ offs,
                       const int2* __restrict__ csr, const float4* __restrict__ b1f4,
                       int4* __restrict__ h1) {
    int wave = threadIdx.x >> 6;
    int lane = threadIdx.x & 63;
    int g    = lane >> 5;        // which edge of the pair
    int sl   = lane & 31;        // int4 slot within the 256-half row
    int c = blockIdx.x * 4 + wave;
    float d = dis[c];
    int4 sp = cfW1[(size_t)nidx[c] * 32 + sl];
    float esum[8] = {0.f, 0.f, 0.f, 0.f, 0.f, 0.f, 0.f, 0.f};
    int a0 = offs[c], a1 = offs[c + 1];
    int s = a0;
    // peel one edge if start is odd (keeps scalar int4 loads 16B-aligned)
    if (s < a1 && (s & 1)) {
        int sb = __builtin_amdgcn_readfirstlane(s);
        int2 e0 = csr[sb];
        int4 v0 = cfW1[(size_t)(e0.x & 1023) * 32 + sl];
        float n = (g == 0) ? __int_as_float(e0.y) : 0.0f;
        acc8(esum, v0, n);
        ++s;
    }
    // main: 4 pairs (8 edges) per batch, 4 int4 gathers in flight
    for (; s + 8 <= a1; s += 8) {
        int sb = __builtin_amdgcn_readfirstlane(s);
        int4 ee[4];
        #pragma unroll
        for (int u = 0; u < 4; ++u) ee[u] = *(const int4*)(csr + sb + 2 * u);
        int4 v[4]; float n[4];
        #pragma unroll
        for (int u = 0; u < 4; ++u) {
            int ex = g ? ee[u].z : ee[u].x;
            int ey = g ? ee[u].w : ee[u].y;
            n[u] = __int_as_float(ey);
            v[u] = cfW1[(size_t)(ex & 1023) * 32 + sl];
        }
        #pragma unroll
        for (int u = 0; u < 4; ++u) acc8(esum, v[u], n[u]);
    }
    // pair tail
    for (; s + 2 <= a1; s += 2) {
        int sb = __builtin_amdgcn_readfirstlane(s);
        int4 ee = *(const int4*)(csr + sb);
        int ex = g ? ee.z : ee.x;
        int ey = g ? ee.w : ee.y;
        int4 v0 = cfW1[(size_t)(ex & 1023) * 32 + sl];
        acc8(esum, v0, __int_as_float(ey));
    }
    // single tail
    if (s < a1) {
        int sb = __builtin_amdgcn_readfirstlane(s);
        int2 e0 = csr[sb];
        int4 v0 = cfW1[(size_t)(e0.x & 1023) * 32 + sl];
        float n = (g == 0) ? __int_as_float(e0.y) : 0.0f;
        acc8(esum, v0, n);
    }
    // combine the two half-wave partial sums
    #pragma unroll
    for (int k = 0; k < 8; ++k) esum[k] += __shfl_xor(esum[k], 32, 64);

    float dd = d * d;
    float2 s0 = __half22float2(*(__half2*)&sp.x);
    float2 s1 = __half22float2(*(__half2*)&sp.y);
    float2 s2 = __half22float2(*(__half2*)&sp.z);
    float2 s3 = __half22float2(*(__half2*)&sp.w);
    float4 bb0 = b1f4[2 * sl];
    float4 bb1 = b1f4[2 * sl + 1];
    float r[8];
    r[0] = bb0.x + s0.x * dd + d * esum[0];
    r[1] = bb0.y + s0.y * dd + d * esum[1];
    r[2] = bb0.z + s1.x * dd + d * esum[2];
    r[3] = bb0.w + s1.y * dd + d * esum[3];
    r[4] = bb1.x + s2.x * dd + d * esum[4];
    r[5] = bb1.y + s2.y * dd + d * esum[5];
    r[6] = bb1.z + s3.x * dd + d * esum[6];
    r[7] = bb1.w + s3.y * dd + d * esum[7];
    #pragma unroll
    for (int k = 0; k < 8; ++k) r[k] = r[k] > 0.f ? r[k] : 0.f;
    float2 p0 = {r[0], r[1]}, p1 = {r[2], r[3]}, p2 = {r[4], r[5]}, p3 = {r[6], r[7]};
    __half2 h0 = __float22half2_rn(p0);
    __half2 h1v = __float22half2_rn(p1);
    __half2 h2 = __float22half2_rn(p2);
    __half2 h3 = __float22half2_rn(p3);
    int4 outv;
    outv.x = *(int*)&h0;
    outv.y = *(int*)&h1v;
    outv.z = *(int*)&h2;
    outv.w = *(int*)&h3;
    if (lane < 32) h1[(size_t)c * 32 + sl] = outv;
}

// ---------------- GEMM2 via MFMA: h1 [N,256] fp16 @ W2 -> xw2h fp16 ---------

__global__ void k_gemm2(const _Float16* __restrict__ h1, const _Float16* __restrict__ W2T,
                        __half* __restrict__ xw2h) {
    int wave = threadIdx.x >> 6;
    int lane = threadIdx.x & 63;
    int quad = lane >> 4;
    int n    = lane & 15;
    int tm   = blockIdx.x * 4 + wave;                  // 16-row tile index
    const _Float16* arow = h1 + (size_t)(tm * 16 + n) * H_DIM;
    half8 a[8];
    #pragma unroll
    for (int kt = 0; kt < 8; ++kt)
        a[kt] = *(const half8*)(arow + kt * 32 + quad * 8);
    #pragma unroll
    for (int nt = 0; nt < 8; ++nt) {
        floatx4 acc = {0.f, 0.f, 0.f, 0.f};
        const _Float16* brow = W2T + (size_t)(nt * 16 + n) * H_DIM;
        #pragma unroll
        for (int kt = 0; kt < 8; ++kt) {
            half8 b = *(const half8*)(brow + kt * 32 + quad * 8);
            acc = __builtin_amdgcn_mfma_f32_16x16x32_f16(a[kt], b, acc, 0, 0, 0);
        }
        #pragma unroll
        for (int r = 0; r < 4; ++r) {
            int rowi = tm * 16 + quad * 4 + r;
            xw2h[(size_t)rowi * O_DIM + nt * 16 + n] = __float2half(acc[r]);
        }
    }
}

// ---------------- layer-2 agg + relu + LDS-reduced pool (R1-exact) ----------

__global__ void k_agg2_pool(const int4* __restrict__ xw2h, const float* __restrict__ b2,
                            const float* __restrict__ dis, const int* __restrict__ offs,
                            const int2* __restrict__ csr, const int* __restrict__ batch,
                            float* __restrict__ pool) {
    __shared__ float red[4][128];
    __shared__ int bgs[4];
    int wave = threadIdx.x >> 6;
    int lane = threadIdx.x & 63;
    int grp  = lane >> 4;        // which edge of the quad
    int sl   = lane & 15;        // int4 slot within the 128-half row
    int c = blockIdx.x * 4 + wave;
    float d = dis[c];
    int4 sp = xw2h[(size_t)c * 16 + sl];
    float esum[8] = {0.f, 0.f, 0.f, 0.f, 0.f, 0.f, 0.f, 0.f};
    int s0 = offs[c], s1 = offs[c + 1];
    int s = s0;
    // main: 4 quads (16 edges) per batch, 4 int4 gathers in flight
    for (; s + 16 <= s1; s += 16) {
        int sb = __builtin_amdgcn_readfirstlane(s);
        int2 e[4];
        #pragma unroll
        for (int u = 0; u < 4; ++u) e[u] = csr[sb + 4 * u + grp];
        int4 v[4];
        #pragma unroll
        for (int u = 0; u < 4; ++u)
            v[u] = xw2h[(size_t)(((unsigned)e[u].x) >> 10) * 16 + sl];
        #pragma unroll
        for (int u = 0; u < 4; ++u) acc8(esum, v[u], __int_as_float(e[u].y));
    }
    // quad tail
    for (; s + 4 <= s1; s += 4) {
        int sb = __builtin_amdgcn_readfirstlane(s);
        int2 e0 = csr[sb + grp];
        int4 v0 = xw2h[(size_t)(((unsigned)e0.x) >> 10) * 16 + sl];
        acc8(esum, v0, __int_as_float(e0.y));
    }
    // remainder 0..3 edges: clamp index, zero weight for invalid lanes
    if (s < s1) {
        int sb = __builtin_amdgcn_readfirstlane(s);
        int idx = sb + grp;
        int idc = idx < s1 ? idx : s1 - 1;
        int2 e0 = csr[idc];
        int4 v0 = xw2h[(size_t)(((unsigned)e0.x) >> 10) * 16 + sl];
        float n = (idx < s1) ? __int_as_float(e0.y) : 0.0f;
        acc8(esum, v0, n);
    }
    // combine the 4 lane-group partial sums
    #pragma unroll
    for (int k = 0; k < 8; ++k) {
        esum[k] += __shfl_xor(esum[k], 16, 64);
        esum[k] += __shfl_xor(esum[k], 32, 64);
    }
    float dd = d * d;
    float2 f0 = __half22float2(*(__half2*)&sp.x);
    float2 f1 = __half22float2(*(__half2*)&sp.y);
    float2 f2 = __half22float2(*(__half2*)&sp.z);
    float2 f3 = __half22float2(*(__half2*)&sp.w);
    float4 bb0 = ((const float4*)b2)[2 * sl];
    float4 bb1 = ((const float4*)b2)[2 * sl + 1];
    float acc[8];
    acc[0] = bb0.x + f0.x * dd + d * esum[0];
    acc[1] = bb0.y + f0.y * dd + d * esum[1];
    acc[2] = bb0.z + f1.x * dd + d * esum[2];
    acc[3] = bb0.w + f1.y * dd + d * esum[3];
    acc[4] = bb1.x + f2.x * dd + d * esum[4];
    acc[5] = bb1.y + f2.y * dd + d * esum[5];
    acc[6] = bb1.z + f3.x * dd + d * esum[6];
    acc[7] = bb1.w + f3.y * dd + d * esum[7];
    #pragma unroll
    for (int k = 0; k < 8; ++k) acc[k] = acc[k] > 0.f ? acc[k] : 0.f;
    if (grp == 0) {
        #pragma unroll
        for (int k = 0; k < 8; ++k) red[wave][8 * sl + k] = acc[k];
    }
    if (lane == 0) bgs[wave] = batch[c];
    __syncthreads();
    if (wave == 0) {
        float2 a;
        a.x = red[0][2 * lane];
        a.y = red[0][2 * lane + 1];
        int cg = bgs[0];
        #pragma unroll
        for (int w = 1; w < 4; ++w) {
            int g = bgs[w];
            float2 r;
            r.x = red[w][2 * lane];
            r.y = red[w][2 * lane + 1];
            if (g == cg) { a.x += r.x; a.y += r.y; }
            else {
                atomicAdd(&pool[cg * O_DIM + 2 * lane], a.x);
                atomicAdd(&pool[cg * O_DIM + 2 * lane + 1], a.y);
                a = r; cg = g;
            }
        }
        atomicAdd(&pool[cg * O_DIM + 2 * lane], a.x);
        atomicAdd(&pool[cg * O_DIM + 2 * lane + 1], a.y);
    }
}

__global__ void k_final(const float* __restrict__ pool, const float* __restrict__ cnt,
                        float* __restrict__ out) {
    int t = blockIdx.x * blockDim.x + threadIdx.x;
    if (t < N_GRAPH * O_DIM) {
        int g = t / O_DIM;
        out[t] = pool[t] / fmaxf(cnt[g], 1.0f);
    }
}

// ---------------- launch ----------------

extern "C" void kernel_launch(void* const* d_in, const int* in_sizes, int n_in,
                              void* d_out, int out_size, void* d_ws, size_t ws_size,
                              hipStream_t stream) {
    const float* cf   = (const float*)d_in[0];   // [V,128]
    const float* W1   = (const float*)d_in[1];   // [128,256]
    const float* b1   = (const float*)d_in[2];   // [256]
    const float* W2   = (const float*)d_in[3];   // [256,128]
    const float* b2   = (const float*)d_in[4];   // [128]
    const float* ew   = (const float*)d_in[5];   // [E]
    const int*   nidx = (const int*)d_in[6];     // [N]
    const int*   eidx = (const int*)d_in[7];     // [2,E]
    const int*   bidx = (const int*)d_in[8];     // [N]
    float* out = (float*)d_out;

    const int* row = eidx;            // source
    const int* col = eidx + N_EDGES;  // target

    // workspace layout (bytes)
    char* ws = (char*)d_ws;
    size_t off = 0;
    int*   hist  = (int*)  (ws + off); off += (size_t)N_NODES * 4;          // 256K
    int*   hoffs = (int*)  (ws + off); off += (size_t)N_NODES * 4;          // 256K
    int*   bsum  = (int*)  (ws + off); off += 4096;
    float* dis   = (float*)(ws + off); off += (size_t)N_NODES * 4;          // 256K
    int*   offs  = (int*)  (ws + off); off += (size_t)(N_NODES + 16) * 4;   // 256K
    int2*  csr   = (int2*) (ws + off); off += (size_t)N_EDGES * 8;          // 16M
    float* pool  = (float*)(ws + off); off += (size_t)(N_GRAPH * O_DIM + N_GRAPH) * 4;
    __half* cfW1 = (__half*)(ws + off); off += (size_t)V_SIZE * H_DIM * 2;  // 512K
    _Float16* W2T = (_Float16*)(ws + off); off += (size_t)O_DIM * H_DIM * 2; // 64K
    off = (off + 255) & ~(size_t)255;
    int2*  part  = (int2*) (ws + off); off += (size_t)N_EDGES * 8;          // 16M
    __half* h1   = (__half*)(ws + off);                                     // 32M
    __half* xw2h = (__half*)part;    // part dead after k_build2
    float* cntf  = pool + N_GRAPH * O_DIM;

    // 1. init (pool zero + counts + cfW1 + W2T) + histogram + partial scan
    k_init<<<256, 256, 0, stream>>>(pool, bidx, cntf, cf, W1, cfW1, W2, W2T);
    k_hist<<<NBLK, 1024, 0, stream>>>(col, hist);
    k_scan1<<<256, 256, 0, stream>>>(hist, hoffs, bsum);

    // 2. LDS-staged partition -> build1 (deg/dis/offs) -> LDS-staged build2
    k_part<<<NBLK, 1024, 0, stream>>>(row, col, ew, nidx, hoffs, bsum, part);
    k_build1<<<256, 1024, 0, stream>>>(bsum, part, dis, offs);
    k_build2<<<256, 1024, 0, stream>>>(bsum, part, dis, offs, csr);

    // 3. layer 1: gather-aggregate from the 512 KB cfW1 table -> h1 (fp16)
    k_agg1<<<N_NODES / 4, 256, 0, stream>>>((const int4*)cfW1, nidx, dis, offs, csr,
                                            (const float4*)b1, (int4*)h1);

    // 4. layer 2: MFMA GEMM2, then aggregate + relu + LDS-reduced pool
    k_gemm2<<<N_NODES / 64, 256, 0, stream>>>((const _Float16*)h1, W2T, xw2h);
    k_agg2_pool<<<N_NODES / 4, 256, 0, stream>>>((const int4*)xw2h, b2, dis, offs, csr,
                                                 bidx, pool);

    // 5. final divide
    k_final<<<(N_GRAPH * O_DIM + 255) / 256, 256, 0, stream>>>(pool, cntf, out);
}

// Round 17
// 304.190 us; speedup vs baseline: 1.4047x; 1.0360x over previous
//
#include <hip/hip_runtime.h>
#include <hip/hip_fp16.h>
#include <math.h>

// Problem constants (match reference)
constexpr int N_NODES = 65536;
constexpr int N_EDGES = 2097152;
constexpr int F_IN    = 128;
constexpr int H_DIM   = 256;
constexpr int O_DIM   = 128;
constexpr int N_GRAPH = 256;
constexpr int V_SIZE  = 1000;

// 256 buckets of 256 nodes (bucket = col>>8); 256 edge-blocks of 8192 edges.
constexpr int EPB  = 8192;
constexpr int NBLK = N_EDGES / EPB;   // 256
constexpr int BUFMAX = 10240;         // build2 LDS segment capacity (22 sigma)

typedef _Float16 half8 __attribute__((ext_vector_type(8)));
typedef float floatx4 __attribute__((ext_vector_type(4)));

// ---------------- fused init + histogram (446 blocks x 1024) ----------------
// blocks 0..255: per-edge-block bucket histogram;
// blocks 256..380: cfW1 = cf@W1 (R9 8-accumulator body, 256 active threads);
// blocks 381..412: W2T transpose; block 413: graph counts; 414..445: pool=0.

__global__ void __launch_bounds__(1024) k_init_hist(
        float* __restrict__ pool, const int* __restrict__ batch,
        float* __restrict__ cntf, const float* __restrict__ cf,
        const float* __restrict__ W1, __half* __restrict__ cfW1,
        const float* __restrict__ W2, _Float16* __restrict__ W2T,
        const int* __restrict__ col, int* __restrict__ hist) {
    __shared__ float xs[8 * F_IN];    // 4 KB (cfW1 blocks)
    __shared__ int h[256];            // (hist blocks)
    int b = blockIdx.x;
    int t = threadIdx.x;
    if (b < 256) {                    // ---- histogram ----
        if (t < 256) h[t] = 0;
        __syncthreads();
        int base = b * EPB;
        #pragma unroll
        for (int i = 0; i < EPB / 1024; ++i)
            atomicAdd(&h[col[base + i * 1024 + t] >> 8], 1);
        __syncthreads();
        if (t < 256) hist[t * NBLK + b] = h[t];   // bucket-major for the scan
        return;
    }
    if (b < 381) {                    // ---- cfW1 (R9-exact body, t<256) ----
        int rb = (b - 256) * 8;
        if (t < 256) {
            #pragma unroll
            for (int p = 0; p < 4; ++p) {
                int idx = p * 256 + t;
                int r = idx >> 7, k = idx & 127;
                xs[idx] = cf[(size_t)(rb + r) * F_IN + k];
            }
        }
        __syncthreads();
        if (t < 256) {
            float acc[8] = {};
            for (int k = 0; k < F_IN; ++k) {
                float w = W1[k * H_DIM + t];
                #pragma unroll
                for (int j = 0; j < 8; ++j) acc[j] += xs[j * F_IN + k] * w;
            }
            #pragma unroll
            for (int j = 0; j < 8; ++j)
                cfW1[(size_t)(rb + j) * H_DIM + t] = __float2half(acc[j]);
        }
        return;
    }
    if (b < 413) {                    // ---- W2T transpose fp32->fp16 ----
        int idx = (b - 381) * 1024 + t;               // 0..32767
        int nn = idx >> 8, kk = idx & 255;
        W2T[idx] = (_Float16)W2[kk * O_DIM + nn];
        return;
    }
    if (b == 413) {                   // ---- per-graph counts ----
        if (t < 256) {
            int g = t;
            int lo = 0, hi = N_NODES;
            while (lo < hi) { int m = (lo + hi) >> 1; if (batch[m] < g) lo = m + 1; else hi = m; }
            int start = lo;
            lo = 0; hi = N_NODES;
            while (lo < hi) { int m = (lo + hi) >> 1; if (batch[m] <= g) lo = m + 1; else hi = m; }
            cntf[g] = (float)(lo - start);
        }
        return;
    }
    {                                 // ---- pool zero (32 blocks) ----
        int idx = (b - 414) * 1024 + t;
        if (idx < N_GRAPH * O_DIM) pool[idx] = 0.0f;
    }
}

// ---------------- scan (partial per-256-chunk + raw chunk sums) -------------

__global__ void k_scan1(const int* __restrict__ in, int* __restrict__ out,
                        int* __restrict__ bsum) {
    __shared__ int s[256];
    int tid = threadIdx.x;
    int i = blockIdx.x * 256 + tid;
    int v = in[i];
    s[tid] = v;
    __syncthreads();
    for (int d = 1; d < 256; d <<= 1) {
        int t = (tid >= d) ? s[tid - d] : 0;
        __syncthreads();
        s[tid] += t;
        __syncthreads();
    }
    out[i] = s[tid] - v;
    if (tid == 255) bsum[blockIdx.x] = s[255];
}

// inline 256-wide exclusive scan of raw bsum -> exc[0..256] (all threads barrier)
__device__ __forceinline__ void scan_bsum(const int* __restrict__ bsum,
                                          int* __restrict__ sbuf,
                                          int* __restrict__ exc, int t) {
    if (t < 256) sbuf[t] = bsum[t];
    __syncthreads();
    for (int d = 1; d < 256; d <<= 1) {
        int x = (t < 256 && t >= d) ? sbuf[t - d] : 0;
        __syncthreads();
        if (t < 256) sbuf[t] += x;
        __syncthreads();
    }
    if (t < 256) exc[t + 1] = sbuf[t];
    if (t == 0) exc[0] = 0;
    __syncthreads();
}

// ---------------- stage C: LDS-staged partition (256 blocks x 1024) ---------
// rec.x = src:16 | dst8:8 | vocab_hi:8 ; rec.y = vocab_lo:2<<16 | ew_fp16:16

__global__ void __launch_bounds__(1024) k_part(
        const int* __restrict__ row, const int* __restrict__ col,
        const float* __restrict__ ew, const int* __restrict__ nidx,
        const int* __restrict__ hoffs, const int* __restrict__ bsum,
        int2* __restrict__ part) {
    __shared__ int2 buf[EPB];            // 64 KB
    __shared__ unsigned char sbk[EPB];   // 8 KB
    __shared__ int h[256];
    __shared__ int lcur[256];
    __shared__ int wbase[256];
    __shared__ int sbuf[256];
    __shared__ int exc[257];
    int t = threadIdx.x;
    int blk = blockIdx.x;
    scan_bsum(bsum, sbuf, exc, t);
    if (t < 256) h[t] = 0;
    __syncthreads();
    int2 recs[8];
    int bks[8];
    int base = blk * EPB;
    #pragma unroll
    for (int i = 0; i < 8; ++i) {
        int e = base + i * 1024 + t;
        int r = row[e], c = col[e];
        unsigned hw = (unsigned)__half_as_ushort(__float2half(ew[e]));
        int vb = nidx[r];
        recs[i].x = (r << 16) | ((c & 255) << 8) | (vb >> 2);
        recs[i].y = (int)(((unsigned)(vb & 3) << 16) | hw);
        bks[i] = c >> 8;
        atomicAdd(&h[bks[i]], 1);
    }
    __syncthreads();
    // exclusive prefix of local counts -> scatter cursors + writeout bases
    if (t < 256) sbuf[t] = h[t];
    __syncthreads();
    for (int d = 1; d < 256; d <<= 1) {
        int x = (t < 256 && t >= d) ? sbuf[t - d] : 0;
        __syncthreads();
        if (t < 256) sbuf[t] += x;
        __syncthreads();
    }
    if (t < 256) {
        int ls = sbuf[t] - h[t];               // local start of bucket t
        lcur[t] = ls;
        wbase[t] = hoffs[t * NBLK + blk] + exc[t] - ls;
    }
    __syncthreads();
    #pragma unroll
    for (int i = 0; i < 8; ++i) {
        int slot = atomicAdd(&lcur[bks[i]], 1);
        buf[slot] = recs[i];
        sbk[slot] = (unsigned char)bks[i];
    }
    __syncthreads();
    // linear drain: consecutive threads hit (mostly) consecutive global slots
    #pragma unroll
    for (int i = 0; i < 8; ++i) {
        int j = i * 1024 + t;
        part[wbase[sbk[j]] + j] = buf[j];
    }
}

// ---------------- stage D1: per-bucket deg/dis + offs (u32 pack) ------------
// dc u32 = count:8 | wsum_fxp16:24 (max deg ~80 << 255; wsum < 2^24). R10-
// validated numerics: deg error <= 6e-4 absolute -> dis error ~1e-5 rel.

__global__ void k_build1(const int* __restrict__ bsum,
                         const int2* __restrict__ part, float* __restrict__ dis,
                         int* __restrict__ offs) {
    __shared__ unsigned dcu[256];
    __shared__ int sc[256];
    __shared__ int sbuf[256];
    __shared__ int exc[257];
    int t = threadIdx.x;
    int bucket = blockIdx.x;
    scan_bsum(bsum, sbuf, exc, t);
    if (t < 256) dcu[t] = 0u;
    __syncthreads();
    int start = exc[bucket];
    int end   = exc[bucket + 1];
    for (int j = start + t; j < end; j += 1024) {
        int2 rec = part[j];
        int dst = (rec.x >> 8) & 255;
        float w = __half2float(__ushort_as_half((unsigned short)(rec.y & 0xFFFF)));
        atomicAdd(&dcu[dst], (1u << 24) | (unsigned)(w * 65536.0f + 0.5f));
    }
    __syncthreads();
    unsigned v = (t < 256) ? dcu[t] : 0u;
    if (t < 256) {
        float deg = 1.0f + (float)(v & 0xFFFFFFu) * (1.0f / 65536.0f);   // self-loop +1
        dis[bucket * 256 + t] = 1.0f / sqrtf(deg);                       // deg >= 1
        sc[t] = (int)(v >> 24);
    }
    __syncthreads();
    for (int d = 1; d < 256; d <<= 1) {
        int x = (t >= d && t < 256) ? sc[t - d] : 0;
        __syncthreads();
        if (t < 256) sc[t] += x;
        __syncthreads();
    }
    if (t < 256) {
        int cnt = (int)(v >> 24);
        offs[bucket * 256 + t] = start + sc[t] - cnt;
    }
    if (bucket == 255 && t == 255) offs[N_NODES] = N_EDGES;
}

// ---------------- stage D2: LDS-staged CSR scatter (256 blocks x 1024) ------

__global__ void __launch_bounds__(1024) k_build2(
        const int* __restrict__ bsum, const int2* __restrict__ part,
        const float* __restrict__ dis, const int* __restrict__ offs,
        int2* __restrict__ csr) {
    __shared__ int2 buf[BUFMAX];   // 80 KB
    __shared__ int cur[256];
    __shared__ int sbuf[256];
    __shared__ int exc[257];
    int t = threadIdx.x;
    int bucket = blockIdx.x;
    scan_bsum(bsum, sbuf, exc, t);
    int start = exc[bucket];
    int end   = exc[bucket + 1];
    int len   = end - start;
    if (len <= BUFMAX) {
        if (t < 256) cur[t] = offs[bucket * 256 + t] - start;
        __syncthreads();
        for (int j = start + t; j < end; j += 1024) {
            int2 rec = part[j];
            int dst = (rec.x >> 8) & 255;
            unsigned src = ((unsigned)rec.x) >> 16;
            int vb = ((rec.x & 255) << 2) | ((rec.y >> 16) & 3);
            float w = __half2float(__ushort_as_half((unsigned short)(rec.y & 0xFFFF)));
            float nm = dis[src] * w;
            int slot = atomicAdd(&cur[dst], 1);
            int2 e;
            e.x = (int)((src << 10) | (unsigned)vb);
            e.y = __float_as_int(nm);
            buf[slot] = e;
        }
        __syncthreads();
        for (int j = t; j < len; j += 1024)
            csr[start + j] = buf[j];
    } else {
        if (t < 256) cur[t] = offs[bucket * 256 + t];
        __syncthreads();
        for (int j = start + t; j < end; j += 1024) {
            int2 rec = part[j];
            int dst = (rec.x >> 8) & 255;
            unsigned src = ((unsigned)rec.x) >> 16;
            int vb = ((rec.x & 255) << 2) | ((rec.y >> 16) & 3);
            float w = __half2float(__ushort_as_half((unsigned short)(rec.y & 0xFFFF)));
            float nm = dis[src] * w;
            int slot = atomicAdd(&cur[dst], 1);
            int2 e;
            e.x = (int)((src << 10) | (unsigned)vb);
            e.y = __float_as_int(nm);
            csr[slot] = e;
        }
    }
}

// 8-half fp16 row-fragment accumulate: e[k] += f32(v[k]) * n
__device__ __forceinline__ void acc8(float* e, int4 v, float n) {
    float2 f0 = __half22float2(*(__half2*)&v.x);
    float2 f1 = __half22float2(*(__half2*)&v.y);
    float2 f2 = __half22float2(*(__half2*)&v.z);
    float2 f3 = __half22float2(*(__half2*)&v.w);
    e[0] += f0.x * n; e[1] += f0.y * n;
    e[2] += f1.x * n; e[3] += f1.y * n;
    e[4] += f2.x * n; e[5] += f2.y * n;
    e[6] += f3.x * n; e[7] += f3.y * n;
}

// ---------------- layer-1: gather-aggregate cfW1 rows -> h1 (R9-exact) ------

__global__ void k_agg1(const int4* __restrict__ cfW1, const int* __restrict__ nidx,
                       const float* __restrict__ dis, const int* __restrict__ offs,
                       const int2* __restrict__ csr, const float4* __restrict__ b1f4,
                       int4* __restrict__ h1) {
    int wave = threadIdx.x >> 6;
    int lane = threadIdx.x & 63;
    int g    = lane >> 5;        // which edge of the pair
    int sl   = lane & 31;        // int4 slot within the 256-half row
    int c = blockIdx.x * 4 + wave;
    float d = dis[c];
    int4 sp = cfW1[(size_t)nidx[c] * 32 + sl];
    float esum[8] = {0.f, 0.f, 0.f, 0.f, 0.f, 0.f, 0.f, 0.f};
    int a0 = offs[c], a1 = offs[c + 1];
    int s = a0;
    // peel one edge if start is odd (keeps scalar int4 loads 16B-aligned)
    if (s < a1 && (s & 1)) {
        int sb = __builtin_amdgcn_readfirstlane(s);
        int2 e0 = csr[sb];
        int4 v0 = cfW1[(size_t)(e0.x & 1023) * 32 + sl];
        float n = (g == 0) ? __int_as_float(e0.y) : 0.0f;
        acc8(esum, v0, n);
        ++s;
    }
    // main: 4 pairs (8 edges) per batch, 4 int4 gathers in flight
    for (; s + 8 <= a1; s += 8) {
        int sb = __builtin_amdgcn_readfirstlane(s);
        int4 ee[4];
        #pragma unroll
        for (int u = 0; u < 4; ++u) ee[u] = *(const int4*)(csr + sb + 2 * u);
        int4 v[4]; float n[4];
        #pragma unroll
        for (int u = 0; u < 4; ++u) {
            int ex = g ? ee[u].z : ee[u].x;
            int ey = g ? ee[u].w : ee[u].y;
            n[u] = __int_as_float(ey);
            v[u] = cfW1[(size_t)(ex & 1023) * 32 + sl];
        }
        #pragma unroll
        for (int u = 0; u < 4; ++u) acc8(esum, v[u], n[u]);
    }
    // pair tail
    for (; s + 2 <= a1; s += 2) {
        int sb = __builtin_amdgcn_readfirstlane(s);
        int4 ee = *(const int4*)(csr + sb);
        int ex = g ? ee.z : ee.x;
        int ey = g ? ee.w : ee.y;
        int4 v0 = cfW1[(size_t)(ex & 1023) * 32 + sl];
        acc8(esum, v0, __int_as_float(ey));
    }
    // single tail
    if (s < a1) {
        int sb = __builtin_amdgcn_readfirstlane(s);
        int2 e0 = csr[sb];
        int4 v0 = cfW1[(size_t)(e0.x & 1023) * 32 + sl];
        float n = (g == 0) ? __int_as_float(e0.y) : 0.0f;
        acc8(esum, v0, n);
    }
    // combine the two half-wave partial sums
    #pragma unroll
    for (int k = 0; k < 8; ++k) esum[k] += __shfl_xor(esum[k], 32, 64);

    float dd = d * d;
    float2 s0 = __half22float2(*(__half2*)&sp.x);
    float2 s1 = __half22float2(*(__half2*)&sp.y);
    float2 s2 = __half22float2(*(__half2*)&sp.z);
    float2 s3 = __half22float2(*(__half2*)&sp.w);
    float4 bb0 = b1f4[2 * sl];
    float4 bb1 = b1f4[2 * sl + 1];
    float r[8];
    r[0] = bb0.x + s0.x * dd + d * esum[0];
    r[1] = bb0.y + s0.y * dd + d * esum[1];
    r[2] = bb0.z + s1.x * dd + d * esum[2];
    r[3] = bb0.w + s1.y * dd + d * esum[3];
    r[4] = bb1.x + s2.x * dd + d * esum[4];
    r[5] = bb1.y + s2.y * dd + d * esum[5];
    r[6] = bb1.z + s3.x * dd + d * esum[6];
    r[7] = bb1.w + s3.y * dd + d * esum[7];
    #pragma unroll
    for (int k = 0; k < 8; ++k) r[k] = r[k] > 0.f ? r[k] : 0.f;
    float2 p0 = {r[0], r[1]}, p1 = {r[2], r[3]}, p2 = {r[4], r[5]}, p3 = {r[6], r[7]};
    __half2 h0 = __float22half2_rn(p0);
    __half2 h1v = __float22half2_rn(p1);
    __half2 h2 = __float22half2_rn(p2);
    __half2 h3 = __float22half2_rn(p3);
    int4 outv;
    outv.x = *(int*)&h0;
    outv.y = *(int*)&h1v;
    outv.z = *(int*)&h2;
    outv.w = *(int*)&h3;
    if (lane < 32) h1[(size_t)c * 32 + sl] = outv;
}

// ---------------- GEMM2 via MFMA: h1 [N,256] fp16 @ W2 -> xw2h fp16 ---------

__global__ void k_gemm2(const _Float16* __restrict__ h1, const _Float16* __restrict__ W2T,
                        __half* __restrict__ xw2h) {
    int wave = threadIdx.x >> 6;
    int lane = threadIdx.x & 63;
    int quad = lane >> 4;
    int n    = lane & 15;
    int tm   = blockIdx.x * 4 + wave;                  // 16-row tile index
    const _Float16* arow = h1 + (size_t)(tm * 16 + n) * H_DIM;
    half8 a[8];
    #pragma unroll
    for (int kt = 0; kt < 8; ++kt)
        a[kt] = *(const half8*)(arow + kt * 32 + quad * 8);
    #pragma unroll
    for (int nt = 0; nt < 8; ++nt) {
        floatx4 acc = {0.f, 0.f, 0.f, 0.f};
        const _Float16* brow = W2T + (size_t)(nt * 16 + n) * H_DIM;
        #pragma unroll
        for (int kt = 0; kt < 8; ++kt) {
            half8 b = *(const half8*)(brow + kt * 32 + quad * 8);
            acc = __builtin_amdgcn_mfma_f32_16x16x32_f16(a[kt], b, acc, 0, 0, 0);
        }
        #pragma unroll
        for (int r = 0; r < 4; ++r) {
            int rowi = tm * 16 + quad * 4 + r;
            xw2h[(size_t)rowi * O_DIM + nt * 16 + n] = __float2half(acc[r]);
        }
    }
}

// ---------------- layer-2 agg + relu + LDS-reduced pool (R1-exact) ----------

__global__ void k_agg2_pool(const int4* __restrict__ xw2h, const float* __restrict__ b2,
                            const float* __restrict__ dis, const int* __restrict__ offs,
                            const int2* __restrict__ csr, const int* __restrict__ batch,
                            float* __restrict__ pool) {
    __shared__ float red[4][128];
    __shared__ int bgs[4];
    int wave = threadIdx.x >> 6;
    int lane = threadIdx.x & 63;
    int grp  = lane >> 4;        // which edge of the quad
    int sl   = lane & 15;        // int4 slot within the 128-half row
    int c = blockIdx.x * 4 + wave;
    float d = dis[c];
    int4 sp = xw2h[(size_t)c * 16 + sl];
    float esum[8] = {0.f, 0.f, 0.f, 0.f, 0.f, 0.f, 0.f, 0.f};
    int s0 = offs[c], s1 = offs[c + 1];
    int s = s0;
    // main: 4 quads (16 edges) per batch, 4 int4 gathers in flight
    for (; s + 16 <= s1; s += 16) {
        int sb = __builtin_amdgcn_readfirstlane(s);
        int2 e[4];
        #pragma unroll
        for (int u = 0; u < 4; ++u) e[u] = csr[sb + 4 * u + grp];
        int4 v[4];
        #pragma unroll
        for (int u = 0; u < 4; ++u)
            v[u] = xw2h[(size_t)(((unsigned)e[u].x) >> 10) * 16 + sl];
        #pragma unroll
        for (int u = 0; u < 4; ++u) acc8(esum, v[u], __int_as_float(e[u].y));
    }
    // quad tail
    for (; s + 4 <= s1; s += 4) {
        int sb = __builtin_amdgcn_readfirstlane(s);
        int2 e0 = csr[sb + grp];
        int4 v0 = xw2h[(size_t)(((unsigned)e0.x) >> 10) * 16 + sl];
        acc8(esum, v0, __int_as_float(e0.y));
    }
    // remainder 0..3 edges: clamp index, zero weight for invalid lanes
    if (s < s1) {
        int sb = __builtin_amdgcn_readfirstlane(s);
        int idx = sb + grp;
        int idc = idx < s1 ? idx : s1 - 1;
        int2 e0 = csr[idc];
        int4 v0 = xw2h[(size_t)(((unsigned)e0.x) >> 10) * 16 + sl];
        float n = (idx < s1) ? __int_as_float(e0.y) : 0.0f;
        acc8(esum, v0, n);
    }
    // combine the 4 lane-group partial sums
    #pragma unroll
    for (int k = 0; k < 8; ++k) {
        esum[k] += __shfl_xor(esum[k], 16, 64);
        esum[k] += __shfl_xor(esum[k], 32, 64);
    }
    float dd = d * d;
    float2 f0 = __half22float2(*(__half2*)&sp.x);
    float2 f1 = __half22float2(*(__half2*)&sp.y);
    float2 f2 = __half22float2(*(__half2*)&sp.z);
    float2 f3 = __half22float2(*(__half2*)&sp.w);
    float4 bb0 = ((const float4*)b2)[2 * sl];
    float4 bb1 = ((const float4*)b2)[2 * sl + 1];
    float acc[8];
    acc[0] = bb0.x + f0.x * dd + d * esum[0];
    acc[1] = bb0.y + f0.y * dd + d * esum[1];
    acc[2] = bb0.z + f1.x * dd + d * esum[2];
    acc[3] = bb0.w + f1.y * dd + d * esum[3];
    acc[4] = bb1.x + f2.x * dd + d * esum[4];
    acc[5] = bb1.y + f2.y * dd + d * esum[5];
    acc[6] = bb1.z + f3.x * dd + d * esum[6];
    acc[7] = bb1.w + f3.y * dd + d * esum[7];
    #pragma unroll
    for (int k = 0; k < 8; ++k) acc[k] = acc[k] > 0.f ? acc[k] : 0.f;
    if (grp == 0) {
        #pragma unroll
        for (int k = 0; k < 8; ++k) red[wave][8 * sl + k] = acc[k];
    }
    if (lane == 0) bgs[wave] = batch[c];
    __syncthreads();
    if (wave == 0) {
        float2 a;
        a.x = red[0][2 * lane];
        a.y = red[0][2 * lane + 1];
        int cg = bgs[0];
        #pragma unroll
        for (int w = 1; w < 4; ++w) {
            int g = bgs[w];
            float2 r;
            r.x = red[w][2 * lane];
            r.y = red[w][2 * lane + 1];
            if (g == cg) { a.x += r.x; a.y += r.y; }
            else {
                atomicAdd(&pool[cg * O_DIM + 2 * lane], a.x);
                atomicAdd(&pool[cg * O_DIM + 2 * lane + 1], a.y);
                a = r; cg = g;
            }
        }
        atomicAdd(&pool[cg * O_DIM + 2 * lane], a.x);
        atomicAdd(&pool[cg * O_DIM + 2 * lane + 1], a.y);
    }
}

__global__ void k_final(const float* __restrict__ pool, const float* __restrict__ cnt,
                        float* __restrict__ out) {
    int t = blockIdx.x * blockDim.x + threadIdx.x;
    if (t < N_GRAPH * O_DIM) {
        int g = t / O_DIM;
        out[t] = pool[t] / fmaxf(cnt[g], 1.0f);
    }
}

// ---------------- launch ----------------

extern "C" void kernel_launch(void* const* d_in, const int* in_sizes, int n_in,
                              void* d_out, int out_size, void* d_ws, size_t ws_size,
                              hipStream_t stream) {
    const float* cf   = (const float*)d_in[0];   // [V,128]
    const float* W1   = (const float*)d_in[1];   // [128,256]
    const float* b1   = (const float*)d_in[2];   // [256]
    const float* W2   = (const float*)d_in[3];   // [256,128]
    const float* b2   = (const float*)d_in[4];   // [128]
    const float* ew   = (const float*)d_in[5];   // [E]
    const int*   nidx = (const int*)d_in[6];     // [N]
    const int*   eidx = (const int*)d_in[7];     // [2,E]
    const int*   bidx = (const int*)d_in[8];     // [N]
    float* out = (float*)d_out;

    const int* row = eidx;            // source
    const int* col = eidx + N_EDGES;  // target

    // workspace layout (bytes)
    char* ws = (char*)d_ws;
    size_t off = 0;
    int*   hist  = (int*)  (ws + off); off += (size_t)N_NODES * 4;          // 256K
    int*   hoffs = (int*)  (ws + off); off += (size_t)N_NODES * 4;          // 256K
    int*   bsum  = (int*)  (ws + off); off += 4096;
    float* dis   = (float*)(ws + off); off += (size_t)N_NODES * 4;          // 256K
    int*   offs  = (int*)  (ws + off); off += (size_t)(N_NODES + 16) * 4;   // 256K
    int2*  csr   = (int2*) (ws + off); off += (size_t)N_EDGES * 8;          // 16M
    float* pool  = (float*)(ws + off); off += (size_t)(N_GRAPH * O_DIM + N_GRAPH) * 4;
    __half* cfW1 = (__half*)(ws + off); off += (size_t)V_SIZE * H_DIM * 2;  // 512K
    _Float16* W2T = (_Float16*)(ws + off); off += (size_t)O_DIM * H_DIM * 2; // 64K
    off = (off + 255) & ~(size_t)255;
    int2*  part  = (int2*) (ws + off); off += (size_t)N_EDGES * 8;          // 16M
    __half* h1   = (__half*)(ws + off);                                     // 32M
    __half* xw2h = (__half*)part;    // part dead after k_build2
    float* cntf  = pool + N_GRAPH * O_DIM;

    // 1. fused init + histogram, then partial scan
    k_init_hist<<<446, 1024, 0, stream>>>(pool, bidx, cntf, cf, W1, cfW1, W2, W2T,
                                          col, hist);
    k_scan1<<<256, 256, 0, stream>>>(hist, hoffs, bsum);

    // 2. LDS-staged partition -> build1 (u32 deg/dis/offs) -> LDS-staged build2
    k_part<<<NBLK, 1024, 0, stream>>>(row, col, ew, nidx, hoffs, bsum, part);
    k_build1<<<256, 1024, 0, stream>>>(bsum, part, dis, offs);
    k_build2<<<256, 1024, 0, stream>>>(bsum, part, dis, offs, csr);

    // 3. layer 1: gather-aggregate from the 512 KB cfW1 table -> h1 (fp16)
    k_agg1<<<N_NODES / 4, 256, 0, stream>>>((const int4*)cfW1, nidx, dis, offs, csr,
                                            (const float4*)b1, (int4*)h1);

    // 4. layer 2: MFMA GEMM2, then aggregate + relu + LDS-reduced pool
    k_gemm2<<<N_NODES / 64, 256, 0, stream>>>((const _Float16*)h1, W2T, xw2h);
    k_agg2_pool<<<N_NODES / 4, 256, 0, stream>>>((const int4*)xw2h, b2, dis, offs, csr,
                                                 bidx, pool);

    // 5. final divide
    k_final<<<(N_GRAPH * O_DIM + 255) / 256, 256, 0, stream>>>(pool, cntf, out);
}